// Round 1
// baseline (465.351 us; speedup 1.0000x reference)
//
#include <hip/hip_runtime.h>
#include <cstdint>
#include <cstddef>

#define B_ 2
#define T_ 2048
#define D_ 2048
#define H_ 16
#define HD_ 128
#define EPS_ 1e-6f
#define QSCALE_ 0.08838834764831845f  // 1/sqrt(128)
#define KVSTRIDE_ (H_ * HD_)          // 2048 elems between consecutive t

typedef unsigned short u16;
typedef short s16x8 __attribute__((ext_vector_type(8)));
typedef float f32x4 __attribute__((ext_vector_type(4)));

__device__ __forceinline__ float bf2f(u16 h) {
  union { unsigned int u; float f; } v;
  v.u = ((unsigned int)h) << 16;
  return v.f;
}
__device__ __forceinline__ u16 f2bf(float f) {
  union { float f; unsigned int u; } v;
  v.f = f;
  unsigned int r = v.u + 0x7FFFu + ((v.u >> 16) & 1u);  // round-to-nearest-even
  return (u16)(r >> 16);
}

// async global->LDS, 16B per lane (LDS dest = wave-uniform base + lane*16)
__device__ __forceinline__ void gload16(const void* g, void* l) {
  __builtin_amdgcn_global_load_lds(
      (const __attribute__((address_space(1))) unsigned int*)g,
      (__attribute__((address_space(3))) unsigned int*)l, 16, 0, 0);
}

// ---------------- fp32 -> bf16 cast ----------------
__global__ void cvt_f32_bf16(const float* __restrict__ in, u16* __restrict__ out, int n4) {
  int i = blockIdx.x * blockDim.x + threadIdx.x;
  if (i < n4) {
    float4 v = ((const float4*)in)[i];
    ((ushort4*)out)[i] = make_ushort4(f2bf(v.x), f2bf(v.y), f2bf(v.z), f2bf(v.w));
  }
}

// ---------------- bf16 GEMM: C[M,N] = A[M,K] * Bm[N,K]^T ----------------
// m97 structure with BK=64: two 128x32 half-tiles staged per barrier period
// (LDS [kc][128][32] keeps m97's bank-verified 64B row stride; 32 MFMA/barrier,
// half the barrier-drain stalls of BK=32). LDS 32 KB total.
template <int OUT_BF16>
__global__ __launch_bounds__(256, 2) void gemm_btn(const u16* __restrict__ A,
                                                   const u16* __restrict__ Bm,
                                                   void* __restrict__ Cout,
                                                   int M, int N, int K) {
  __shared__ u16 As[2 * 128 * 32];
  __shared__ u16 Bs[2 * 128 * 32];
  const int tid = threadIdx.x;
  const int w = tid >> 6, lane = tid & 63, quad = lane >> 4, c = lane & 15;
  const int wm = w & 1, wn = w >> 1;
  const int m0 = blockIdx.y * 128, n0 = blockIdx.x * 128;

  f32x4 acc[4][4];
#pragma unroll
  for (int i = 0; i < 4; ++i)
#pragma unroll
    for (int j = 0; j < 4; ++j) acc[i][j] = (f32x4){0.f, 0.f, 0.f, 0.f};

  for (int k0 = 0; k0 < K; k0 += 64) {
    __syncthreads();
#pragma unroll
    for (int i = 0; i < 4; ++i) {
      int chunk = (w * 4 + i) * 64 + lane;   // 0..1023
      int kc = chunk >> 9;                    // half-tile select (LDS-contiguous)
      int within = chunk & 511;
      int row = within >> 2, cc = within & 3; // 128 rows x 4 8-elem chunks
      gload16(A + (size_t)(m0 + row) * K + k0 + kc * 32 + cc * 8, (void*)(As + chunk * 8));
      gload16(Bm + (size_t)(n0 + row) * K + k0 + kc * 32 + cc * 8, (void*)(Bs + chunk * 8));
    }
    __syncthreads();
#pragma unroll
    for (int kc = 0; kc < 2; ++kc) {
      s16x8 af[4], bf[4];
#pragma unroll
      for (int mi = 0; mi < 4; ++mi)
        af[mi] = *(const s16x8*)(As + kc * 4096 + (wm * 64 + mi * 16 + c) * 32 + quad * 8);
#pragma unroll
      for (int ni = 0; ni < 4; ++ni)
        bf[ni] = *(const s16x8*)(Bs + kc * 4096 + (wn * 64 + ni * 16 + c) * 32 + quad * 8);
#pragma unroll
      for (int mi = 0; mi < 4; ++mi)
#pragma unroll
        for (int ni = 0; ni < 4; ++ni)
          acc[mi][ni] = __builtin_amdgcn_mfma_f32_16x16x32_bf16(af[mi], bf[ni], acc[mi][ni], 0, 0, 0);
    }
  }

#pragma unroll
  for (int mi = 0; mi < 4; ++mi)
#pragma unroll
    for (int ni = 0; ni < 4; ++ni)
#pragma unroll
      for (int r = 0; r < 4; ++r) {
        int row = m0 + wm * 64 + mi * 16 + quad * 4 + r;
        int col = n0 + wn * 64 + ni * 16 + c;
        float v = acc[mi][ni][r];
        if (OUT_BF16)
          ((u16*)Cout)[(size_t)row * N + col] = f2bf(v);
        else
          ((float*)Cout)[(size_t)row * N + col] = v;
      }
}

// ---------------- fused RMSNorm + interleaved RoPE (in-place on bf16) ----------------
__global__ void rmsnorm_rope(u16* __restrict__ x, const float* __restrict__ nw, float outscale) {
  const int tid = threadIdx.x;
  const int w = tid >> 6, lane = tid & 63;
  const int vec = blockIdx.x * 4 + w;   // (b*T + t)*H + h
  const int t = (vec >> 4) & (T_ - 1);  // /H % T
  u16* base = x + (size_t)vec * HD_;
  unsigned int pk = *(const unsigned int*)(base + lane * 2);
  float e = bf2f((u16)(pk & 0xFFFFu));
  float o = bf2f((u16)(pk >> 16));
  float ss = e * e + o * o;
#pragma unroll
  for (int off = 1; off < 64; off <<= 1) ss += __shfl_xor(ss, off, 64);
  float rn = rsqrtf(ss * (1.0f / HD_) + EPS_);
  float we = nw[lane * 2], wo = nw[lane * 2 + 1];
  e = e * rn * we;
  o = o * rn * wo;
  float freq = expf(-(float)lane * (9.210340371976184f / 64.0f));  // 10000^(-lane/64)
  float ang = (float)t * freq;
  float sn, cs;
  sincosf(ang, &sn, &cs);
  float re = (e * cs - o * sn) * outscale;
  float ro = (e * sn + o * cs) * outscale;
  *(unsigned int*)(base + lane * 2) = ((unsigned int)f2bf(ro) << 16) | (unsigned int)f2bf(re);
}

// ---------------- causal flash attention, Br=Bc=64, bf16 MFMA ----------------
// R3 changes vs R2:
//  - pads dropped, XOR slot-swizzle (T2): LDS 40960 B -> exactly 4 blocks/CU,
//    fragment ds_read_b128 spread over all 8 bank groups (conflict-free)
//  - staging via global_load_lds w=16 with INVERSE-swizzled per-lane global src
//    (linear LDS dest, m173 pattern) -- no VGPR round-trip
//  - post-Ps barrier removed (Ps is wave-private: wave w writes/reads rows 16w..16w+15)
//  - __launch_bounds__(256,4): all 1024 blocks co-resident, causal imbalance overlaps
// Q scaled by 1/sqrt(HD), layout (B,T,H,HD). K layout (B,T,H,HD).
// V is TRANSPOSED: Vt[o=h*128+d][tok=b*2048+t]  (t contiguous) -> vector B-frags.
__global__ __launch_bounds__(256, 4) void attn_fwd(const u16* __restrict__ Q,
                                                   const u16* __restrict__ Kg,
                                                   const u16* __restrict__ Vt,
                                                   u16* __restrict__ O) {
  __shared__ u16 Ks[64 * 128];   // K rows (s-major, d contig), slot-swizzled
  __shared__ u16 Vts[128 * 64];  // V^T rows (d-major, s contig), slot-swizzled
  __shared__ u16 Ps[64 * 64];    // P round-trip (wave-private), slot-swizzled
  const int tid = threadIdx.x;
  const int w = tid >> 6, lane = tid & 63, quad = lane >> 4, c = lane & 15;
  const int c7 = (c & 7) * 8;    // read-side XOR term (row % 8 == c % 8 for all frag reads)
  const int bid = blockIdx.x;
  const int qt = 31 - (bid >> 5);  // heavy (qt=31) blocks dispatch first
  const int h = bid & 15;
  const int b = (bid >> 4) & 1;
  const int q0 = qt * 64;

  // Q fragments, kept in registers (rows w*16+c, A-layout)
  s16x8 qf[4];
  const u16* qbase = Q + ((size_t)(b * T_ + q0 + w * 16 + c) * H_ + h) * HD_;
#pragma unroll
  for (int kk = 0; kk < 4; ++kk) qf[kk] = *(const s16x8*)(qbase + kk * 32 + quad * 8);

  f32x4 of[8];
#pragma unroll
  for (int i = 0; i < 8; ++i) of[i] = (f32x4){0.f, 0.f, 0.f, 0.f};
  float m_i[4] = {-1e30f, -1e30f, -1e30f, -1e30f};
  float l_i[4] = {0.f, 0.f, 0.f, 0.f};

  const u16* kbase = Kg + ((size_t)b * T_ * H_ + h) * HD_;
  const u16* vtbase = Vt + (size_t)(h * HD_) * (B_ * T_) + (size_t)b * T_;

  for (int j = 0; j <= qt; ++j) {
    __syncthreads();  // all waves done reading tile j-1
    // stage K tile (64 x 128) and Vt tile (128 x 64) via async DMA.
    // LDS dest is linear in lane (chunk*16B); swizzle is applied by reading the
    // global slot (slot' ^ row%8) into LDS slot slot'.
    const u16* krow = kbase + (size_t)(j * 64) * KVSTRIDE_;
    const u16* vrow = vtbase + j * 64;
#pragma unroll
    for (int i = 0; i < 4; ++i) {
      int chunk = i * 256 + tid;  // 0..1023
      int krowi = chunk >> 4, kslot = (chunk & 15) ^ (krowi & 7);
      gload16(krow + (size_t)krowi * KVSTRIDE_ + kslot * 8, (void*)(Ks + chunk * 8));
      int vrowi = chunk >> 3, vslot = (chunk & 7) ^ (vrowi & 7);
      gload16(vrow + (size_t)vrowi * (B_ * T_) + vslot * 8, (void*)(Vts + chunk * 8));
    }
    __syncthreads();  // drains vmcnt -> tile j ready

    // S = Q K^T  (rows w*16+quad*4+r, cols ni*16+c); Ks row = ni*16+c -> row%8 == c%8
    f32x4 sf[4];
#pragma unroll
    for (int ni = 0; ni < 4; ++ni) {
      f32x4 a = (f32x4){0.f, 0.f, 0.f, 0.f};
#pragma unroll
      for (int kk = 0; kk < 4; ++kk) {
        s16x8 bfr = *(const s16x8*)(&Ks[(ni * 16 + c) * 128 + ((kk * 32 + quad * 8) ^ c7)]);
        a = __builtin_amdgcn_mfma_f32_16x16x32_bf16(qf[kk], bfr, a, 0, 0, 0);
      }
      sf[ni] = a;
    }
    // causal mask (only needed on the diagonal tile)
    if (j == qt) {
#pragma unroll
      for (int ni = 0; ni < 4; ++ni)
#pragma unroll
        for (int r = 0; r < 4; ++r) {
          int rowg = w * 16 + quad * 4 + r;
          int colg = ni * 16 + c;
          if (colg > rowg) sf[ni][r] = -1e30f;
        }
    }
    // online softmax (rows live across 16 lanes sharing `quad`)
    float mc[4];
#pragma unroll
    for (int r = 0; r < 4; ++r)
      mc[r] = fmaxf(fmaxf(sf[0][r], sf[1][r]), fmaxf(sf[2][r], sf[3][r]));
#pragma unroll
    for (int off = 1; off < 16; off <<= 1)
#pragma unroll
      for (int r = 0; r < 4; ++r) mc[r] = fmaxf(mc[r], __shfl_xor(mc[r], off, 64));
#pragma unroll
    for (int r = 0; r < 4; ++r) {
      float mnew = fmaxf(m_i[r], mc[r]);
      float alpha = __expf(m_i[r] - mnew);
      m_i[r] = mnew;
      l_i[r] *= alpha;
#pragma unroll
      for (int ot = 0; ot < 8; ++ot) of[ot][r] *= alpha;
    }
    float rs[4] = {0.f, 0.f, 0.f, 0.f};
#pragma unroll
    for (int ni = 0; ni < 4; ++ni)
#pragma unroll
      for (int r = 0; r < 4; ++r) {
        float p = __expf(sf[ni][r] - m_i[r]);
        sf[ni][r] = p;
        rs[r] += p;
      }
#pragma unroll
    for (int off = 1; off < 16; off <<= 1)
#pragma unroll
      for (int r = 0; r < 4; ++r) rs[r] += __shfl_xor(rs[r], off, 64);
#pragma unroll
    for (int r = 0; r < 4; ++r) l_i[r] += rs[r];
    // write P (C-layout -> LDS, rows w*16+quad*4+r), swizzled on elem bits 3-5.
    // Wave-private (wave w touches only rows 16w..16w+15): NO barrier needed.
#pragma unroll
    for (int ni = 0; ni < 4; ++ni)
#pragma unroll
      for (int r = 0; r < 4; ++r) {
        int row = w * 16 + quad * 4 + r;
        Ps[row * 64 + ((ni * 16 + c) ^ ((row & 7) * 8))] = f2bf(sf[ni][r]);
      }
    // O += P V  (A-frag of P: rows w*16+c -> row%8 == c%8; B-frag of V likewise)
    s16x8 pa[2];
    pa[0] = *(const s16x8*)(&Ps[(w * 16 + c) * 64 + ((quad * 8) ^ c7)]);
    pa[1] = *(const s16x8*)(&Ps[(w * 16 + c) * 64 + ((32 + quad * 8) ^ c7)]);
#pragma unroll
    for (int ot = 0; ot < 8; ++ot) {
#pragma unroll
      for (int kk = 0; kk < 2; ++kk) {
        s16x8 vfr = *(const s16x8*)(&Vts[(ot * 16 + c) * 64 + ((kk * 32 + quad * 8) ^ c7)]);
        of[ot] = __builtin_amdgcn_mfma_f32_16x16x32_bf16(pa[kk], vfr, of[ot], 0, 0, 0);
      }
    }
  }

  // epilogue: O /= l, store bf16 ctx (flat (B,T,H,HD) layout)
  float inv[4];
#pragma unroll
  for (int r = 0; r < 4; ++r) inv[r] = 1.0f / l_i[r];
  u16* obase = O + ((size_t)(b * T_ + q0) * H_ + h) * HD_;
#pragma unroll
  for (int ot = 0; ot < 8; ++ot)
#pragma unroll
    for (int r = 0; r < 4; ++r)
      obase[(size_t)(w * 16 + quad * 4 + r) * KVSTRIDE_ + ot * 16 + c] = f2bf(of[ot][r] * inv[r]);
}

// ---------------- launch ----------------
extern "C" void kernel_launch(void* const* d_in, const int* in_sizes, int n_in,
                              void* d_out, int out_size, void* d_ws, size_t ws_size,
                              hipStream_t stream) {
  const float* x = (const float*)d_in[0];
  const float* Wq = (const float*)d_in[1];
  const float* Wk = (const float*)d_in[2];
  const float* Wv = (const float*)d_in[3];
  const float* Wo = (const float*)d_in[4];
  const float* qw = (const float*)d_in[5];
  const float* kw = (const float*)d_in[6];
  float* out = (float*)d_out;

  const size_t xE = (size_t)B_ * T_ * D_;   // 8388608
  const size_t wE = (size_t)D_ * H_ * HD_;  // 4194304
  const size_t need = xE * 2 * 5 + wE * 2 * 4;  // ~112 MB
  if (ws_size < need) return;

  char* ws = (char*)d_ws;
  u16* xb = (u16*)ws;   ws += xE * 2;
  u16* wqb = (u16*)ws;  ws += wE * 2;
  u16* wkb = (u16*)ws;  ws += wE * 2;
  u16* wvb = (u16*)ws;  ws += wE * 2;
  u16* wob = (u16*)ws;  ws += wE * 2;
  u16* qb = (u16*)ws;   ws += xE * 2;
  u16* kb = (u16*)ws;   ws += xE * 2;
  u16* vtb = (u16*)ws;  ws += xE * 2;   // V^T: [H*HD][B*T]
  u16* ctxb = (u16*)ws; ws += xE * 2;

  cvt_f32_bf16<<<xE / 1024, 256, 0, stream>>>(x, xb, (int)(xE / 4));
  cvt_f32_bf16<<<wE / 1024, 256, 0, stream>>>(Wq, wqb, (int)(wE / 4));
  cvt_f32_bf16<<<wE / 1024, 256, 0, stream>>>(Wk, wkb, (int)(wE / 4));
  cvt_f32_bf16<<<wE / 1024, 256, 0, stream>>>(Wv, wvb, (int)(wE / 4));
  cvt_f32_bf16<<<wE / 1024, 256, 0, stream>>>(Wo, wob, (int)(wE / 4));

  dim3 gg(16, 32);  // (N/128, M/128)
  gemm_btn<1><<<gg, 256, 0, stream>>>(xb, wqb, qb, 4096, 2048, 2048);
  gemm_btn<1><<<gg, 256, 0, stream>>>(xb, wkb, kb, 4096, 2048, 2048);
  // V^T = Wv * x^T : M=2048 (o), N=4096 (tokens)
  dim3 ggv(32, 16);
  gemm_btn<1><<<ggv, 256, 0, stream>>>(wvb, xb, vtb, 2048, 4096, 2048);

  rmsnorm_rope<<<16384, 256, 0, stream>>>(qb, qw, QSCALE_);
  rmsnorm_rope<<<16384, 256, 0, stream>>>(kb, kw, 1.0f);

  attn_fwd<<<B_ * H_ * (T_ / 64), 256, 0, stream>>>(qb, kb, vtb, ctxb);

  gemm_btn<0><<<gg, 256, 0, stream>>>(ctxb, wob, out, 4096, 2048, 2048);
}

// Round 2
// 421.984 us; speedup vs baseline: 1.1028x; 1.1028x over previous
//
#include <hip/hip_runtime.h>
#include <cstdint>
#include <cstddef>

#define B_ 2
#define T_ 2048
#define D_ 2048
#define H_ 16
#define HD_ 128
#define EPS_ 1e-6f
#define QSCALE_ 0.08838834764831845f  // 1/sqrt(128)
#define KVSTRIDE_ (H_ * HD_)          // 2048 elems between consecutive t

typedef unsigned short u16;
typedef short s16x8 __attribute__((ext_vector_type(8)));
typedef float f32x4 __attribute__((ext_vector_type(4)));

__device__ __forceinline__ float bf2f(u16 h) {
  union { unsigned int u; float f; } v;
  v.u = ((unsigned int)h) << 16;
  return v.f;
}
__device__ __forceinline__ u16 f2bf(float f) {
  union { float f; unsigned int u; } v;
  v.f = f;
  unsigned int r = v.u + 0x7FFFu + ((v.u >> 16) & 1u);  // round-to-nearest-even
  return (u16)(r >> 16);
}

// async global->LDS, 16B per lane (LDS dest = wave-uniform base + lane*16)
__device__ __forceinline__ void gload16(const void* g, void* l) {
  __builtin_amdgcn_global_load_lds(
      (const __attribute__((address_space(1))) unsigned int*)g,
      (__attribute__((address_space(3))) unsigned int*)l, 16, 0, 0);
}

// ---------------- fp32 -> bf16 cast ----------------
__global__ void cvt_f32_bf16(const float* __restrict__ in, u16* __restrict__ out, int n4) {
  int i = blockIdx.x * blockDim.x + threadIdx.x;
  if (i < n4) {
    float4 v = ((const float4*)in)[i];
    ((ushort4*)out)[i] = make_ushort4(f2bf(v.x), f2bf(v.y), f2bf(v.z), f2bf(v.w));
  }
}

// ---------------- bf16 GEMM: C[M,N] = A[M,K] * Bm[N,K]^T ----------------
// m97 structure with BK=64: two 128x32 half-tiles staged per barrier period
// (LDS [kc][128][32] keeps m97's bank-verified 64B row stride; 32 MFMA/barrier,
// half the barrier-drain stalls of BK=32). LDS 32 KB total.
template <int OUT_BF16>
__global__ __launch_bounds__(256, 2) void gemm_btn(const u16* __restrict__ A,
                                                   const u16* __restrict__ Bm,
                                                   void* __restrict__ Cout,
                                                   int M, int N, int K) {
  __shared__ u16 As[2 * 128 * 32];
  __shared__ u16 Bs[2 * 128 * 32];
  const int tid = threadIdx.x;
  const int w = tid >> 6, lane = tid & 63, quad = lane >> 4, c = lane & 15;
  const int wm = w & 1, wn = w >> 1;
  const int m0 = blockIdx.y * 128, n0 = blockIdx.x * 128;

  f32x4 acc[4][4];
#pragma unroll
  for (int i = 0; i < 4; ++i)
#pragma unroll
    for (int j = 0; j < 4; ++j) acc[i][j] = (f32x4){0.f, 0.f, 0.f, 0.f};

  for (int k0 = 0; k0 < K; k0 += 64) {
    __syncthreads();
#pragma unroll
    for (int i = 0; i < 4; ++i) {
      int chunk = (w * 4 + i) * 64 + lane;   // 0..1023
      int kc = chunk >> 9;                    // half-tile select (LDS-contiguous)
      int within = chunk & 511;
      int row = within >> 2, cc = within & 3; // 128 rows x 4 8-elem chunks
      gload16(A + (size_t)(m0 + row) * K + k0 + kc * 32 + cc * 8, (void*)(As + chunk * 8));
      gload16(Bm + (size_t)(n0 + row) * K + k0 + kc * 32 + cc * 8, (void*)(Bs + chunk * 8));
    }
    __syncthreads();
#pragma unroll
    for (int kc = 0; kc < 2; ++kc) {
      s16x8 af[4], bf[4];
#pragma unroll
      for (int mi = 0; mi < 4; ++mi)
        af[mi] = *(const s16x8*)(As + kc * 4096 + (wm * 64 + mi * 16 + c) * 32 + quad * 8);
#pragma unroll
      for (int ni = 0; ni < 4; ++ni)
        bf[ni] = *(const s16x8*)(Bs + kc * 4096 + (wn * 64 + ni * 16 + c) * 32 + quad * 8);
#pragma unroll
      for (int mi = 0; mi < 4; ++mi)
#pragma unroll
        for (int ni = 0; ni < 4; ++ni)
          acc[mi][ni] = __builtin_amdgcn_mfma_f32_16x16x32_bf16(af[mi], bf[ni], acc[mi][ni], 0, 0, 0);
    }
  }

#pragma unroll
  for (int mi = 0; mi < 4; ++mi)
#pragma unroll
    for (int ni = 0; ni < 4; ++ni)
#pragma unroll
      for (int r = 0; r < 4; ++r) {
        int row = m0 + wm * 64 + mi * 16 + quad * 4 + r;
        int col = n0 + wn * 64 + ni * 16 + c;
        float v = acc[mi][ni][r];
        if (OUT_BF16)
          ((u16*)Cout)[(size_t)row * N + col] = f2bf(v);
        else
          ((float*)Cout)[(size_t)row * N + col] = v;
      }
}

// ---------------- fused RMSNorm + interleaved RoPE (in-place on bf16) ----------------
__global__ void rmsnorm_rope(u16* __restrict__ x, const float* __restrict__ nw, float outscale) {
  const int tid = threadIdx.x;
  const int w = tid >> 6, lane = tid & 63;
  const int vec = blockIdx.x * 4 + w;   // (b*T + t)*H + h
  const int t = (vec >> 4) & (T_ - 1);  // /H % T
  u16* base = x + (size_t)vec * HD_;
  unsigned int pk = *(const unsigned int*)(base + lane * 2);
  float e = bf2f((u16)(pk & 0xFFFFu));
  float o = bf2f((u16)(pk >> 16));
  float ss = e * e + o * o;
#pragma unroll
  for (int off = 1; off < 64; off <<= 1) ss += __shfl_xor(ss, off, 64);
  float rn = rsqrtf(ss * (1.0f / HD_) + EPS_);
  float we = nw[lane * 2], wo = nw[lane * 2 + 1];
  e = e * rn * we;
  o = o * rn * wo;
  float freq = expf(-(float)lane * (9.210340371976184f / 64.0f));  // 10000^(-lane/64)
  float ang = (float)t * freq;
  float sn, cs;
  sincosf(ang, &sn, &cs);
  float re = (e * cs - o * sn) * outscale;
  float ro = (e * sn + o * cs) * outscale;
  *(unsigned int*)(base + lane * 2) = ((unsigned int)f2bf(ro) << 16) | (unsigned int)f2bf(re);
}

// ---------------- causal flash attention, Br=Bc=64, bf16 MFMA ----------------
// R4: identical to R3 EXCEPT __launch_bounds__ back to (256,2).
// R3's (256,4) made the compiler cram into 64 VGPR -> scratch spills
// (WRITE_SIZE 16->40 MB, +47us). With cap 256 the kernel fits in ~80 VGPR,
// and HW occupancy can still reach 4 blocks/CU (4 x 40960 B = 160 KiB LDS).
// Kept from R3:
//  - pads dropped, XOR slot-swizzle (T2): conflict cycles halved vs R2
//  - staging via global_load_lds w=16 with inverse-swizzled per-lane global src
//  - post-Ps barrier removed (Ps is wave-private)
// Q scaled by 1/sqrt(HD), layout (B,T,H,HD). K layout (B,T,H,HD).
// V is TRANSPOSED: Vt[o=h*128+d][tok=b*2048+t]  (t contiguous) -> vector B-frags.
__global__ __launch_bounds__(256, 2) void attn_fwd(const u16* __restrict__ Q,
                                                   const u16* __restrict__ Kg,
                                                   const u16* __restrict__ Vt,
                                                   u16* __restrict__ O) {
  __shared__ u16 Ks[64 * 128];   // K rows (s-major, d contig), slot-swizzled
  __shared__ u16 Vts[128 * 64];  // V^T rows (d-major, s contig), slot-swizzled
  __shared__ u16 Ps[64 * 64];    // P round-trip (wave-private), slot-swizzled
  const int tid = threadIdx.x;
  const int w = tid >> 6, lane = tid & 63, quad = lane >> 4, c = lane & 15;
  const int c7 = (c & 7) * 8;    // read-side XOR term (row % 8 == c % 8 for all frag reads)
  const int bid = blockIdx.x;
  const int qt = 31 - (bid >> 5);  // heavy (qt=31) blocks dispatch first
  const int h = bid & 15;
  const int b = (bid >> 4) & 1;
  const int q0 = qt * 64;

  // Q fragments, kept in registers (rows w*16+c, A-layout)
  s16x8 qf[4];
  const u16* qbase = Q + ((size_t)(b * T_ + q0 + w * 16 + c) * H_ + h) * HD_;
#pragma unroll
  for (int kk = 0; kk < 4; ++kk) qf[kk] = *(const s16x8*)(qbase + kk * 32 + quad * 8);

  f32x4 of[8];
#pragma unroll
  for (int i = 0; i < 8; ++i) of[i] = (f32x4){0.f, 0.f, 0.f, 0.f};
  float m_i[4] = {-1e30f, -1e30f, -1e30f, -1e30f};
  float l_i[4] = {0.f, 0.f, 0.f, 0.f};

  const u16* kbase = Kg + ((size_t)b * T_ * H_ + h) * HD_;
  const u16* vtbase = Vt + (size_t)(h * HD_) * (B_ * T_) + (size_t)b * T_;

  for (int j = 0; j <= qt; ++j) {
    __syncthreads();  // all waves done reading tile j-1
    // stage K tile (64 x 128) and Vt tile (128 x 64) via async DMA.
    // LDS dest is linear in lane (chunk*16B); swizzle is applied by reading the
    // global slot (slot' ^ row%8) into LDS slot slot'.
    const u16* krow = kbase + (size_t)(j * 64) * KVSTRIDE_;
    const u16* vrow = vtbase + j * 64;
#pragma unroll
    for (int i = 0; i < 4; ++i) {
      int chunk = i * 256 + tid;  // 0..1023
      int krowi = chunk >> 4, kslot = (chunk & 15) ^ (krowi & 7);
      gload16(krow + (size_t)krowi * KVSTRIDE_ + kslot * 8, (void*)(Ks + chunk * 8));
      int vrowi = chunk >> 3, vslot = (chunk & 7) ^ (vrowi & 7);
      gload16(vrow + (size_t)vrowi * (B_ * T_) + vslot * 8, (void*)(Vts + chunk * 8));
    }
    __syncthreads();  // drains vmcnt -> tile j ready

    // S = Q K^T  (rows w*16+quad*4+r, cols ni*16+c); Ks row = ni*16+c -> row%8 == c%8
    f32x4 sf[4];
#pragma unroll
    for (int ni = 0; ni < 4; ++ni) {
      f32x4 a = (f32x4){0.f, 0.f, 0.f, 0.f};
#pragma unroll
      for (int kk = 0; kk < 4; ++kk) {
        s16x8 bfr = *(const s16x8*)(&Ks[(ni * 16 + c) * 128 + ((kk * 32 + quad * 8) ^ c7)]);
        a = __builtin_amdgcn_mfma_f32_16x16x32_bf16(qf[kk], bfr, a, 0, 0, 0);
      }
      sf[ni] = a;
    }
    // causal mask (only needed on the diagonal tile)
    if (j == qt) {
#pragma unroll
      for (int ni = 0; ni < 4; ++ni)
#pragma unroll
        for (int r = 0; r < 4; ++r) {
          int rowg = w * 16 + quad * 4 + r;
          int colg = ni * 16 + c;
          if (colg > rowg) sf[ni][r] = -1e30f;
        }
    }
    // online softmax (rows live across 16 lanes sharing `quad`)
    float mc[4];
#pragma unroll
    for (int r = 0; r < 4; ++r)
      mc[r] = fmaxf(fmaxf(sf[0][r], sf[1][r]), fmaxf(sf[2][r], sf[3][r]));
#pragma unroll
    for (int off = 1; off < 16; off <<= 1)
#pragma unroll
      for (int r = 0; r < 4; ++r) mc[r] = fmaxf(mc[r], __shfl_xor(mc[r], off, 64));
#pragma unroll
    for (int r = 0; r < 4; ++r) {
      float mnew = fmaxf(m_i[r], mc[r]);
      float alpha = __expf(m_i[r] - mnew);
      m_i[r] = mnew;
      l_i[r] *= alpha;
#pragma unroll
      for (int ot = 0; ot < 8; ++ot) of[ot][r] *= alpha;
    }
    float rs[4] = {0.f, 0.f, 0.f, 0.f};
#pragma unroll
    for (int ni = 0; ni < 4; ++ni)
#pragma unroll
      for (int r = 0; r < 4; ++r) {
        float p = __expf(sf[ni][r] - m_i[r]);
        sf[ni][r] = p;
        rs[r] += p;
      }
#pragma unroll
    for (int off = 1; off < 16; off <<= 1)
#pragma unroll
      for (int r = 0; r < 4; ++r) rs[r] += __shfl_xor(rs[r], off, 64);
#pragma unroll
    for (int r = 0; r < 4; ++r) l_i[r] += rs[r];
    // write P (C-layout -> LDS, rows w*16+quad*4+r), swizzled on elem bits 3-5.
    // Wave-private (wave w touches only rows 16w..16w+15): NO barrier needed.
#pragma unroll
    for (int ni = 0; ni < 4; ++ni)
#pragma unroll
      for (int r = 0; r < 4; ++r) {
        int row = w * 16 + quad * 4 + r;
        Ps[row * 64 + ((ni * 16 + c) ^ ((row & 7) * 8))] = f2bf(sf[ni][r]);
      }
    // O += P V  (A-frag of P: rows w*16+c -> row%8 == c%8; B-frag of V likewise)
    s16x8 pa[2];
    pa[0] = *(const s16x8*)(&Ps[(w * 16 + c) * 64 + ((quad * 8) ^ c7)]);
    pa[1] = *(const s16x8*)(&Ps[(w * 16 + c) * 64 + ((32 + quad * 8) ^ c7)]);
#pragma unroll
    for (int ot = 0; ot < 8; ++ot) {
#pragma unroll
      for (int kk = 0; kk < 2; ++kk) {
        s16x8 vfr = *(const s16x8*)(&Vts[(ot * 16 + c) * 64 + ((kk * 32 + quad * 8) ^ c7)]);
        of[ot] = __builtin_amdgcn_mfma_f32_16x16x32_bf16(pa[kk], vfr, of[ot], 0, 0, 0);
      }
    }
  }

  // epilogue: O /= l, store bf16 ctx (flat (B,T,H,HD) layout)
  float inv[4];
#pragma unroll
  for (int r = 0; r < 4; ++r) inv[r] = 1.0f / l_i[r];
  u16* obase = O + ((size_t)(b * T_ + q0) * H_ + h) * HD_;
#pragma unroll
  for (int ot = 0; ot < 8; ++ot)
#pragma unroll
    for (int r = 0; r < 4; ++r)
      obase[(size_t)(w * 16 + quad * 4 + r) * KVSTRIDE_ + ot * 16 + c] = f2bf(of[ot][r] * inv[r]);
}

// ---------------- launch ----------------
extern "C" void kernel_launch(void* const* d_in, const int* in_sizes, int n_in,
                              void* d_out, int out_size, void* d_ws, size_t ws_size,
                              hipStream_t stream) {
  const float* x = (const float*)d_in[0];
  const float* Wq = (const float*)d_in[1];
  const float* Wk = (const float*)d_in[2];
  const float* Wv = (const float*)d_in[3];
  const float* Wo = (const float*)d_in[4];
  const float* qw = (const float*)d_in[5];
  const float* kw = (const float*)d_in[6];
  float* out = (float*)d_out;

  const size_t xE = (size_t)B_ * T_ * D_;   // 8388608
  const size_t wE = (size_t)D_ * H_ * HD_;  // 4194304
  const size_t need = xE * 2 * 5 + wE * 2 * 4;  // ~112 MB
  if (ws_size < need) return;

  char* ws = (char*)d_ws;
  u16* xb = (u16*)ws;   ws += xE * 2;
  u16* wqb = (u16*)ws;  ws += wE * 2;
  u16* wkb = (u16*)ws;  ws += wE * 2;
  u16* wvb = (u16*)ws;  ws += wE * 2;
  u16* wob = (u16*)ws;  ws += wE * 2;
  u16* qb = (u16*)ws;   ws += xE * 2;
  u16* kb = (u16*)ws;   ws += xE * 2;
  u16* vtb = (u16*)ws;  ws += xE * 2;   // V^T: [H*HD][B*T]
  u16* ctxb = (u16*)ws; ws += xE * 2;

  cvt_f32_bf16<<<xE / 1024, 256, 0, stream>>>(x, xb, (int)(xE / 4));
  cvt_f32_bf16<<<wE / 1024, 256, 0, stream>>>(Wq, wqb, (int)(wE / 4));
  cvt_f32_bf16<<<wE / 1024, 256, 0, stream>>>(Wk, wkb, (int)(wE / 4));
  cvt_f32_bf16<<<wE / 1024, 256, 0, stream>>>(Wv, wvb, (int)(wE / 4));
  cvt_f32_bf16<<<wE / 1024, 256, 0, stream>>>(Wo, wob, (int)(wE / 4));

  dim3 gg(16, 32);  // (N/128, M/128)
  gemm_btn<1><<<gg, 256, 0, stream>>>(xb, wqb, qb, 4096, 2048, 2048);
  gemm_btn<1><<<gg, 256, 0, stream>>>(xb, wkb, kb, 4096, 2048, 2048);
  // V^T = Wv * x^T : M=2048 (o), N=4096 (tokens)
  dim3 ggv(32, 16);
  gemm_btn<1><<<ggv, 256, 0, stream>>>(wvb, xb, vtb, 2048, 4096, 2048);

  rmsnorm_rope<<<16384, 256, 0, stream>>>(qb, qw, QSCALE_);
  rmsnorm_rope<<<16384, 256, 0, stream>>>(kb, kw, 1.0f);

  attn_fwd<<<B_ * H_ * (T_ / 64), 256, 0, stream>>>(qb, kb, vtb, ctxb);

  gemm_btn<0><<<gg, 256, 0, stream>>>(ctxb, wob, out, 4096, 2048, 2048);
}

// Round 3
// 411.770 us; speedup vs baseline: 1.1301x; 1.0248x over previous
//
#include <hip/hip_runtime.h>
#include <cstdint>
#include <cstddef>

#define B_ 2
#define T_ 2048
#define D_ 2048
#define H_ 16
#define HD_ 128
#define EPS_ 1e-6f
#define QSCALE_ 0.08838834764831845f  // 1/sqrt(128)
#define KVSTRIDE_ (H_ * HD_)          // 2048 elems between consecutive t

typedef unsigned short u16;
typedef short s16x8 __attribute__((ext_vector_type(8)));
typedef float f32x4 __attribute__((ext_vector_type(4)));

__device__ __forceinline__ float bf2f(u16 h) {
  union { unsigned int u; float f; } v;
  v.u = ((unsigned int)h) << 16;
  return v.f;
}
__device__ __forceinline__ u16 f2bf(float f) {
  union { float f; unsigned int u; } v;
  v.f = f;
  unsigned int r = v.u + 0x7FFFu + ((v.u >> 16) & 1u);  // round-to-nearest-even
  return (u16)(r >> 16);
}

// async global->LDS, 16B per lane (LDS dest = wave-uniform base + lane*16)
__device__ __forceinline__ void gload16(const void* g, void* l) {
  __builtin_amdgcn_global_load_lds(
      (const __attribute__((address_space(1))) unsigned int*)g,
      (__attribute__((address_space(3))) unsigned int*)l, 16, 0, 0);
}

// ---------------- fp32 -> bf16 cast ----------------
__global__ void cvt_f32_bf16(const float* __restrict__ in, u16* __restrict__ out, int n4) {
  int i = blockIdx.x * blockDim.x + threadIdx.x;
  if (i < n4) {
    float4 v = ((const float4*)in)[i];
    ((ushort4*)out)[i] = make_ushort4(f2bf(v.x), f2bf(v.y), f2bf(v.z), f2bf(v.w));
  }
}

// ---------------- bf16 GEMM: C[M,N] = A[M,K] * Bm[N,K]^T ----------------
// m97 structure with BK=64: two 128x32 half-tiles staged per barrier period
// (LDS [kc][128][32] keeps m97's bank-verified 64B row stride; 32 MFMA/barrier,
// half the barrier-drain stalls of BK=32). LDS 32 KB total.
template <int OUT_BF16>
__global__ __launch_bounds__(256, 2) void gemm_btn(const u16* __restrict__ A,
                                                   const u16* __restrict__ Bm,
                                                   void* __restrict__ Cout,
                                                   int M, int N, int K) {
  __shared__ u16 As[2 * 128 * 32];
  __shared__ u16 Bs[2 * 128 * 32];
  const int tid = threadIdx.x;
  const int w = tid >> 6, lane = tid & 63, quad = lane >> 4, c = lane & 15;
  const int wm = w & 1, wn = w >> 1;
  const int m0 = blockIdx.y * 128, n0 = blockIdx.x * 128;

  f32x4 acc[4][4];
#pragma unroll
  for (int i = 0; i < 4; ++i)
#pragma unroll
    for (int j = 0; j < 4; ++j) acc[i][j] = (f32x4){0.f, 0.f, 0.f, 0.f};

  for (int k0 = 0; k0 < K; k0 += 64) {
    __syncthreads();
#pragma unroll
    for (int i = 0; i < 4; ++i) {
      int chunk = (w * 4 + i) * 64 + lane;   // 0..1023
      int kc = chunk >> 9;                    // half-tile select (LDS-contiguous)
      int within = chunk & 511;
      int row = within >> 2, cc = within & 3; // 128 rows x 4 8-elem chunks
      gload16(A + (size_t)(m0 + row) * K + k0 + kc * 32 + cc * 8, (void*)(As + chunk * 8));
      gload16(Bm + (size_t)(n0 + row) * K + k0 + kc * 32 + cc * 8, (void*)(Bs + chunk * 8));
    }
    __syncthreads();
#pragma unroll
    for (int kc = 0; kc < 2; ++kc) {
      s16x8 af[4], bf[4];
#pragma unroll
      for (int mi = 0; mi < 4; ++mi)
        af[mi] = *(const s16x8*)(As + kc * 4096 + (wm * 64 + mi * 16 + c) * 32 + quad * 8);
#pragma unroll
      for (int ni = 0; ni < 4; ++ni)
        bf[ni] = *(const s16x8*)(Bs + kc * 4096 + (wn * 64 + ni * 16 + c) * 32 + quad * 8);
#pragma unroll
      for (int mi = 0; mi < 4; ++mi)
#pragma unroll
        for (int ni = 0; ni < 4; ++ni)
          acc[mi][ni] = __builtin_amdgcn_mfma_f32_16x16x32_bf16(af[mi], bf[ni], acc[mi][ni], 0, 0, 0);
    }
  }

#pragma unroll
  for (int mi = 0; mi < 4; ++mi)
#pragma unroll
    for (int ni = 0; ni < 4; ++ni)
#pragma unroll
      for (int r = 0; r < 4; ++r) {
        int row = m0 + wm * 64 + mi * 16 + quad * 4 + r;
        int col = n0 + wn * 64 + ni * 16 + c;
        float v = acc[mi][ni][r];
        if (OUT_BF16)
          ((u16*)Cout)[(size_t)row * N + col] = f2bf(v);
        else
          ((float*)Cout)[(size_t)row * N + col] = v;
      }
}

// ---------------- fused RMSNorm + interleaved RoPE (in-place on bf16) ----------------
__global__ void rmsnorm_rope(u16* __restrict__ x, const float* __restrict__ nw, float outscale) {
  const int tid = threadIdx.x;
  const int w = tid >> 6, lane = tid & 63;
  const int vec = blockIdx.x * 4 + w;   // (b*T + t)*H + h
  const int t = (vec >> 4) & (T_ - 1);  // /H % T
  u16* base = x + (size_t)vec * HD_;
  unsigned int pk = *(const unsigned int*)(base + lane * 2);
  float e = bf2f((u16)(pk & 0xFFFFu));
  float o = bf2f((u16)(pk >> 16));
  float ss = e * e + o * o;
#pragma unroll
  for (int off = 1; off < 64; off <<= 1) ss += __shfl_xor(ss, off, 64);
  float rn = rsqrtf(ss * (1.0f / HD_) + EPS_);
  float we = nw[lane * 2], wo = nw[lane * 2 + 1];
  e = e * rn * we;
  o = o * rn * wo;
  float freq = expf(-(float)lane * (9.210340371976184f / 64.0f));  // 10000^(-lane/64)
  float ang = (float)t * freq;
  float sn, cs;
  sincosf(ang, &sn, &cs);
  float re = (e * cs - o * sn) * outscale;
  float ro = (e * sn + o * cs) * outscale;
  *(unsigned int*)(base + lane * 2) = ((unsigned int)f2bf(ro) << 16) | (unsigned int)f2bf(re);
}

// ---------------- causal flash attention, Br=Bc=64, bf16 MFMA ----------------
// R5 changes vs R4 (R4 showed: conflict-halving + barrier removal = 0 gain ->
// latency-bound on the per-iteration chain, not LDS/barrier-bound):
//  - T3-minimum 2-phase prefetch: K/V double-buffered (LDS 72 KiB, 2 blk/CU);
//    tile j+1's global_load_lds issued BEFORE computing tile j; the single
//    end-of-iter __syncthreads (compiler emits vmcnt(0) there) drains loads
//    that had the whole compute phase in flight -> load latency off the path.
//  - deferred l-reduction: per-lane partial lp[r] = lp*alpha + sum(own 4 p);
//    the 4-round shfl_xor sum runs ONCE in the epilogue (alpha is lane-uniform
//    because m is max-reduced across the 16 c-lanes). Removes ~160 dependent
//    cycles per iteration from the softmax chain.
// Kept: XOR slot-swizzle, DMA staging w/ inverse-swizzled source, wave-private
// Ps (no barrier), launch_bounds(256,2) (R3 taught: (256,4) -> 64 VGPR spills).
__global__ __launch_bounds__(256, 2) void attn_fwd(const u16* __restrict__ Q,
                                                   const u16* __restrict__ Kg,
                                                   const u16* __restrict__ Vt,
                                                   u16* __restrict__ O) {
  __shared__ u16 Ks[2][64 * 128];   // K rows (s-major, d contig), slot-swizzled
  __shared__ u16 Vts[2][128 * 64];  // V^T rows (d-major, s contig), slot-swizzled
  __shared__ u16 Ps[64 * 64];       // P round-trip (wave-private), slot-swizzled
  const int tid = threadIdx.x;
  const int w = tid >> 6, lane = tid & 63, quad = lane >> 4, c = lane & 15;
  const int c7 = (c & 7) * 8;    // read-side XOR term (row % 8 == c % 8 for all frag reads)
  const int bid = blockIdx.x;
  const int qt = 31 - (bid >> 5);  // heavy (qt=31) blocks dispatch first
  const int h = bid & 15;
  const int b = (bid >> 4) & 1;
  const int q0 = qt * 64;

  // Q fragments, kept in registers (rows w*16+c, A-layout)
  s16x8 qf[4];
  const u16* qbase = Q + ((size_t)(b * T_ + q0 + w * 16 + c) * H_ + h) * HD_;
#pragma unroll
  for (int kk = 0; kk < 4; ++kk) qf[kk] = *(const s16x8*)(qbase + kk * 32 + quad * 8);

  f32x4 of[8];
#pragma unroll
  for (int i = 0; i < 8; ++i) of[i] = (f32x4){0.f, 0.f, 0.f, 0.f};
  float m_i[4] = {-1e30f, -1e30f, -1e30f, -1e30f};
  float lp[4] = {0.f, 0.f, 0.f, 0.f};  // PER-LANE partial of l (reduced in epilogue)

  const u16* kbase = Kg + ((size_t)b * T_ * H_ + h) * HD_;
  const u16* vtbase = Vt + (size_t)(h * HD_) * (B_ * T_) + (size_t)b * T_;

  // stage K tile (64 x 128) and Vt tile (128 x 64) via async DMA into buf.
  // LDS dest is linear in lane (chunk*16B); swizzle applied by reading the
  // global slot (slot' ^ row%8) into LDS slot slot'.
  auto STAGE = [&](int j, int buf) {
    const u16* krow = kbase + (size_t)(j * 64) * KVSTRIDE_;
    const u16* vrow = vtbase + j * 64;
#pragma unroll
    for (int i = 0; i < 4; ++i) {
      int chunk = i * 256 + tid;  // 0..1023
      int krowi = chunk >> 4, kslot = (chunk & 15) ^ (krowi & 7);
      gload16(krow + (size_t)krowi * KVSTRIDE_ + kslot * 8, (void*)(&Ks[buf][0] + chunk * 8));
      int vrowi = chunk >> 3, vslot = (chunk & 7) ^ (vrowi & 7);
      gload16(vrow + (size_t)vrowi * (B_ * T_) + vslot * 8, (void*)(&Vts[buf][0] + chunk * 8));
    }
  };

  STAGE(0, 0);
  __syncthreads();  // vmcnt(0) drain -> tile 0 ready
  int cur = 0;

  for (int j = 0; j <= qt; ++j) {
    // issue NEXT tile's loads; they complete while we compute tile j
    if (j < qt) STAGE(j + 1, cur ^ 1);

    // S = Q K^T  (rows w*16+quad*4+r, cols ni*16+c); Ks row = ni*16+c -> row%8 == c%8
    f32x4 sf[4];
#pragma unroll
    for (int ni = 0; ni < 4; ++ni) {
      f32x4 a = (f32x4){0.f, 0.f, 0.f, 0.f};
#pragma unroll
      for (int kk = 0; kk < 4; ++kk) {
        s16x8 bfr = *(const s16x8*)(&Ks[cur][(ni * 16 + c) * 128 + ((kk * 32 + quad * 8) ^ c7)]);
        a = __builtin_amdgcn_mfma_f32_16x16x32_bf16(qf[kk], bfr, a, 0, 0, 0);
      }
      sf[ni] = a;
    }
    // causal mask (only needed on the diagonal tile)
    if (j == qt) {
#pragma unroll
      for (int ni = 0; ni < 4; ++ni)
#pragma unroll
        for (int r = 0; r < 4; ++r) {
          int rowg = w * 16 + quad * 4 + r;
          int colg = ni * 16 + c;
          if (colg > rowg) sf[ni][r] = -1e30f;
        }
    }
    // online softmax (rows live across 16 lanes sharing `quad`)
    float mc[4];
#pragma unroll
    for (int r = 0; r < 4; ++r)
      mc[r] = fmaxf(fmaxf(sf[0][r], sf[1][r]), fmaxf(sf[2][r], sf[3][r]));
#pragma unroll
    for (int off = 1; off < 16; off <<= 1)
#pragma unroll
      for (int r = 0; r < 4; ++r) mc[r] = fmaxf(mc[r], __shfl_xor(mc[r], off, 64));
#pragma unroll
    for (int r = 0; r < 4; ++r) {
      float mnew = fmaxf(m_i[r], mc[r]);
      float alpha = __expf(m_i[r] - mnew);
      m_i[r] = mnew;
      lp[r] *= alpha;
#pragma unroll
      for (int ot = 0; ot < 8; ++ot) of[ot][r] *= alpha;
    }
    // p values + LOCAL l partial (no cross-lane sum here; deferred to epilogue)
#pragma unroll
    for (int ni = 0; ni < 4; ++ni)
#pragma unroll
      for (int r = 0; r < 4; ++r) {
        float p = __expf(sf[ni][r] - m_i[r]);
        sf[ni][r] = p;
        lp[r] += p;
      }
    // write P (C-layout -> LDS, rows w*16+quad*4+r), swizzled on elem bits 3-5.
    // Wave-private (wave w touches only rows 16w..16w+15): NO barrier needed.
#pragma unroll
    for (int ni = 0; ni < 4; ++ni)
#pragma unroll
      for (int r = 0; r < 4; ++r) {
        int row = w * 16 + quad * 4 + r;
        Ps[row * 64 + ((ni * 16 + c) ^ ((row & 7) * 8))] = f2bf(sf[ni][r]);
      }
    // O += P V  (A-frag of P: rows w*16+c -> row%8 == c%8; B-frag of V likewise)
    s16x8 pa[2];
    pa[0] = *(const s16x8*)(&Ps[(w * 16 + c) * 64 + ((quad * 8) ^ c7)]);
    pa[1] = *(const s16x8*)(&Ps[(w * 16 + c) * 64 + ((32 + quad * 8) ^ c7)]);
#pragma unroll
    for (int ot = 0; ot < 8; ++ot) {
#pragma unroll
      for (int kk = 0; kk < 2; ++kk) {
        s16x8 vfr = *(const s16x8*)(&Vts[cur][(ot * 16 + c) * 64 + ((kk * 32 + quad * 8) ^ c7)]);
        of[ot] = __builtin_amdgcn_mfma_f32_16x16x32_bf16(pa[kk], vfr, of[ot], 0, 0, 0);
      }
    }

    // single barrier per iteration: compiler emits s_waitcnt vmcnt(0) lgkmcnt(0)
    // here, draining the prefetch (which had the whole compute phase in flight)
    // and fencing buf reuse across waves.
    __syncthreads();
    cur ^= 1;
  }

  // epilogue: reduce l partials across the 16 c-lanes, then O /= l, store bf16 ctx
#pragma unroll
  for (int off = 1; off < 16; off <<= 1)
#pragma unroll
    for (int r = 0; r < 4; ++r) lp[r] += __shfl_xor(lp[r], off, 64);
  float inv[4];
#pragma unroll
  for (int r = 0; r < 4; ++r) inv[r] = 1.0f / lp[r];
  u16* obase = O + ((size_t)(b * T_ + q0) * H_ + h) * HD_;
#pragma unroll
  for (int ot = 0; ot < 8; ++ot)
#pragma unroll
    for (int r = 0; r < 4; ++r)
      obase[(size_t)(w * 16 + quad * 4 + r) * KVSTRIDE_ + ot * 16 + c] = f2bf(of[ot][r] * inv[r]);
}

// ---------------- launch ----------------
extern "C" void kernel_launch(void* const* d_in, const int* in_sizes, int n_in,
                              void* d_out, int out_size, void* d_ws, size_t ws_size,
                              hipStream_t stream) {
  const float* x = (const float*)d_in[0];
  const float* Wq = (const float*)d_in[1];
  const float* Wk = (const float*)d_in[2];
  const float* Wv = (const float*)d_in[3];
  const float* Wo = (const float*)d_in[4];
  const float* qw = (const float*)d_in[5];
  const float* kw = (const float*)d_in[6];
  float* out = (float*)d_out;

  const size_t xE = (size_t)B_ * T_ * D_;   // 8388608
  const size_t wE = (size_t)D_ * H_ * HD_;  // 4194304
  const size_t need = xE * 2 * 5 + wE * 2 * 4;  // ~112 MB
  if (ws_size < need) return;

  char* ws = (char*)d_ws;
  u16* xb = (u16*)ws;   ws += xE * 2;
  u16* wqb = (u16*)ws;  ws += wE * 2;
  u16* wkb = (u16*)ws;  ws += wE * 2;
  u16* wvb = (u16*)ws;  ws += wE * 2;
  u16* wob = (u16*)ws;  ws += wE * 2;
  u16* qb = (u16*)ws;   ws += xE * 2;
  u16* kb = (u16*)ws;   ws += xE * 2;
  u16* vtb = (u16*)ws;  ws += xE * 2;   // V^T: [H*HD][B*T]
  u16* ctxb = (u16*)ws; ws += xE * 2;

  cvt_f32_bf16<<<xE / 1024, 256, 0, stream>>>(x, xb, (int)(xE / 4));
  cvt_f32_bf16<<<wE / 1024, 256, 0, stream>>>(Wq, wqb, (int)(wE / 4));
  cvt_f32_bf16<<<wE / 1024, 256, 0, stream>>>(Wk, wkb, (int)(wE / 4));
  cvt_f32_bf16<<<wE / 1024, 256, 0, stream>>>(Wv, wvb, (int)(wE / 4));
  cvt_f32_bf16<<<wE / 1024, 256, 0, stream>>>(Wo, wob, (int)(wE / 4));

  dim3 gg(16, 32);  // (N/128, M/128)
  gemm_btn<1><<<gg, 256, 0, stream>>>(xb, wqb, qb, 4096, 2048, 2048);
  gemm_btn<1><<<gg, 256, 0, stream>>>(xb, wkb, kb, 4096, 2048, 2048);
  // V^T = Wv * x^T : M=2048 (o), N=4096 (tokens)
  dim3 ggv(32, 16);
  gemm_btn<1><<<ggv, 256, 0, stream>>>(wvb, xb, vtb, 2048, 4096, 2048);

  rmsnorm_rope<<<16384, 256, 0, stream>>>(qb, qw, QSCALE_);
  rmsnorm_rope<<<16384, 256, 0, stream>>>(kb, kw, 1.0f);

  attn_fwd<<<B_ * H_ * (T_ / 64), 256, 0, stream>>>(qb, kb, vtb, ctxb);

  gemm_btn<0><<<gg, 256, 0, stream>>>(ctxb, wob, out, 4096, 2048, 2048);
}

// Round 4
// 397.751 us; speedup vs baseline: 1.1700x; 1.0352x over previous
//
#include <hip/hip_runtime.h>
#include <cstdint>
#include <cstddef>

#define B_ 2
#define T_ 2048
#define D_ 2048
#define H_ 16
#define HD_ 128
#define EPS_ 1e-6f
#define QSCALE_ 0.08838834764831845f  // 1/sqrt(128)
#define KVSTRIDE_ (H_ * HD_)          // 2048 elems between consecutive t

typedef unsigned short u16;
typedef short s16x8 __attribute__((ext_vector_type(8)));
typedef float f32x4 __attribute__((ext_vector_type(4)));

__device__ __forceinline__ float bf2f(u16 h) {
  union { unsigned int u; float f; } v;
  v.u = ((unsigned int)h) << 16;
  return v.f;
}
__device__ __forceinline__ u16 f2bf(float f) {
  union { float f; unsigned int u; } v;
  v.f = f;
  unsigned int r = v.u + 0x7FFFu + ((v.u >> 16) & 1u);  // round-to-nearest-even
  return (u16)(r >> 16);
}

// async global->LDS, 16B per lane (LDS dest = wave-uniform base + lane*16)
__device__ __forceinline__ void gload16(const void* g, void* l) {
  __builtin_amdgcn_global_load_lds(
      (const __attribute__((address_space(1))) unsigned int*)g,
      (__attribute__((address_space(3))) unsigned int*)l, 16, 0, 0);
}

// ---------------- fp32 -> bf16 cast ----------------
__global__ void cvt_f32_bf16(const float* __restrict__ in, u16* __restrict__ out, int n4) {
  int i = blockIdx.x * blockDim.x + threadIdx.x;
  if (i < n4) {
    float4 v = ((const float4*)in)[i];
    ((ushort4*)out)[i] = make_ushort4(f2bf(v.x), f2bf(v.y), f2bf(v.z), f2bf(v.w));
  }
}

// ---------------- bf16 GEMM: C[M,N] = A[M,K] * Bm[N,K]^T ----------------
// R6: T3-minimum 2-phase prefetch (the R5 attn lever, ported):
//   - LDS double-buffered (64 KiB, 2 blocks/CU): As/Bs[2][2][128][32]
//   - per K-tile: STAGE(t+1 -> buf^1) issued FIRST, then ds_read all frags,
//     then 32 MFMA, then ONE barrier (compiler emits vmcnt(0)+lgkmcnt(0)
//     there) -> the prefetch drain has the whole compute phase of cover.
//     Old structure drained immediately after issue (latency fully exposed,
//     the reason these N=2048-class shapes sat at ~500 TF).
//   - buffer-reuse safety: STAGE(t+1 -> buf^1) vs reads of tile t-1 (same
//     buffer) are separated by iter t-1's end barrier.
// MODE: 0 = f32 out, 1 = bf16 out, 2 = QK-split (bf16; n0<2048 -> Cout,
// else Cout2 with col-2048; both stride 2048). n0 is block-uniform.
template <int MODE>
__global__ __launch_bounds__(256, 2) void gemm_btn(const u16* __restrict__ A,
                                                   const u16* __restrict__ Bm,
                                                   void* __restrict__ Cout,
                                                   void* __restrict__ Cout2,
                                                   int M, int N, int K) {
  __shared__ u16 As[2][2 * 128 * 32];
  __shared__ u16 Bs[2][2 * 128 * 32];
  const int tid = threadIdx.x;
  const int w = tid >> 6, lane = tid & 63, quad = lane >> 4, c = lane & 15;
  const int wm = w & 1, wn = w >> 1;
  const int m0 = blockIdx.y * 128, n0 = blockIdx.x * 128;
  const int NT = K >> 6;

  f32x4 acc[4][4];
#pragma unroll
  for (int i = 0; i < 4; ++i)
#pragma unroll
    for (int j = 0; j < 4; ++j) acc[i][j] = (f32x4){0.f, 0.f, 0.f, 0.f};

  // stage one 128x64 A-tile + B-tile into buf (layout [kc][128][32], 64B rows)
  auto STAGE = [&](int t, int buf) {
    int k0 = t << 6;
#pragma unroll
    for (int i = 0; i < 4; ++i) {
      int chunk = (w * 4 + i) * 64 + lane;    // 0..1023
      int kc = chunk >> 9;                    // half-tile select (LDS-contiguous)
      int within = chunk & 511;
      int row = within >> 2, cc = within & 3; // 128 rows x 4 8-elem chunks
      gload16(A + (size_t)(m0 + row) * K + k0 + kc * 32 + cc * 8, (void*)(&As[buf][0] + chunk * 8));
      gload16(Bm + (size_t)(n0 + row) * K + k0 + kc * 32 + cc * 8, (void*)(&Bs[buf][0] + chunk * 8));
    }
  };

  STAGE(0, 0);
  __syncthreads();  // vmcnt(0) drain -> tile 0 ready
  int cur = 0;

  for (int t = 0; t < NT; ++t) {
    // issue next tile's DMA first; it lands under this tile's compute
    if (t + 1 < NT) STAGE(t + 1, cur ^ 1);

    s16x8 af[4][2], bf[4][2];
#pragma unroll
    for (int kc = 0; kc < 2; ++kc) {
#pragma unroll
      for (int mi = 0; mi < 4; ++mi)
        af[mi][kc] = *(const s16x8*)(&As[cur][0] + kc * 4096 + (wm * 64 + mi * 16 + c) * 32 + quad * 8);
#pragma unroll
      for (int ni = 0; ni < 4; ++ni)
        bf[ni][kc] = *(const s16x8*)(&Bs[cur][0] + kc * 4096 + (wn * 64 + ni * 16 + c) * 32 + quad * 8);
    }
#pragma unroll
    for (int kc = 0; kc < 2; ++kc)
#pragma unroll
      for (int mi = 0; mi < 4; ++mi)
#pragma unroll
        for (int ni = 0; ni < 4; ++ni)
          acc[mi][ni] = __builtin_amdgcn_mfma_f32_16x16x32_bf16(af[mi][kc], bf[ni][kc], acc[mi][ni], 0, 0, 0);

    // single barrier/K-tile: drains the prefetch (covered by the MFMAs above)
    // and fences buffer reuse across waves.
    __syncthreads();
    cur ^= 1;
  }

  // epilogue
  u16* dst16 = (u16*)Cout;
  int coloff = 0, nstride = N;
  if (MODE == 2) {
    nstride = 2048;
    if (n0 >= 2048) { dst16 = (u16*)Cout2; coloff = -2048; }
  }
#pragma unroll
  for (int mi = 0; mi < 4; ++mi)
#pragma unroll
    for (int ni = 0; ni < 4; ++ni)
#pragma unroll
      for (int r = 0; r < 4; ++r) {
        int row = m0 + wm * 64 + mi * 16 + quad * 4 + r;
        int col = n0 + wn * 64 + ni * 16 + c + coloff;
        float v = acc[mi][ni][r];
        if (MODE == 0)
          ((float*)Cout)[(size_t)row * N + col] = v;
        else
          dst16[(size_t)row * nstride + col] = f2bf(v);
      }
}

// ---------------- fused RMSNorm + interleaved RoPE (in-place on bf16) ----------------
__global__ void rmsnorm_rope(u16* __restrict__ x, const float* __restrict__ nw, float outscale) {
  const int tid = threadIdx.x;
  const int w = tid >> 6, lane = tid & 63;
  const int vec = blockIdx.x * 4 + w;   // (b*T + t)*H + h
  const int t = (vec >> 4) & (T_ - 1);  // /H % T
  u16* base = x + (size_t)vec * HD_;
  unsigned int pk = *(const unsigned int*)(base + lane * 2);
  float e = bf2f((u16)(pk & 0xFFFFu));
  float o = bf2f((u16)(pk >> 16));
  float ss = e * e + o * o;
#pragma unroll
  for (int off = 1; off < 64; off <<= 1) ss += __shfl_xor(ss, off, 64);
  float rn = rsqrtf(ss * (1.0f / HD_) + EPS_);
  float we = nw[lane * 2], wo = nw[lane * 2 + 1];
  e = e * rn * we;
  o = o * rn * wo;
  float freq = expf(-(float)lane * (9.210340371976184f / 64.0f));  // 10000^(-lane/64)
  float ang = (float)t * freq;
  float sn, cs;
  sincosf(ang, &sn, &cs);
  float re = (e * cs - o * sn) * outscale;
  float ro = (e * sn + o * cs) * outscale;
  *(unsigned int*)(base + lane * 2) = ((unsigned int)f2bf(ro) << 16) | (unsigned int)f2bf(re);
}

// ---------------- causal flash attention, Br=Bc=64, bf16 MFMA (R5, unchanged) ----------------
__global__ __launch_bounds__(256, 2) void attn_fwd(const u16* __restrict__ Q,
                                                   const u16* __restrict__ Kg,
                                                   const u16* __restrict__ Vt,
                                                   u16* __restrict__ O) {
  __shared__ u16 Ks[2][64 * 128];   // K rows (s-major, d contig), slot-swizzled
  __shared__ u16 Vts[2][128 * 64];  // V^T rows (d-major, s contig), slot-swizzled
  __shared__ u16 Ps[64 * 64];       // P round-trip (wave-private), slot-swizzled
  const int tid = threadIdx.x;
  const int w = tid >> 6, lane = tid & 63, quad = lane >> 4, c = lane & 15;
  const int c7 = (c & 7) * 8;    // read-side XOR term (row % 8 == c % 8 for all frag reads)
  const int bid = blockIdx.x;
  const int qt = 31 - (bid >> 5);  // heavy (qt=31) blocks dispatch first
  const int h = bid & 15;
  const int b = (bid >> 4) & 1;
  const int q0 = qt * 64;

  // Q fragments, kept in registers (rows w*16+c, A-layout)
  s16x8 qf[4];
  const u16* qbase = Q + ((size_t)(b * T_ + q0 + w * 16 + c) * H_ + h) * HD_;
#pragma unroll
  for (int kk = 0; kk < 4; ++kk) qf[kk] = *(const s16x8*)(qbase + kk * 32 + quad * 8);

  f32x4 of[8];
#pragma unroll
  for (int i = 0; i < 8; ++i) of[i] = (f32x4){0.f, 0.f, 0.f, 0.f};
  float m_i[4] = {-1e30f, -1e30f, -1e30f, -1e30f};
  float lp[4] = {0.f, 0.f, 0.f, 0.f};  // PER-LANE partial of l (reduced in epilogue)

  const u16* kbase = Kg + ((size_t)b * T_ * H_ + h) * HD_;
  const u16* vtbase = Vt + (size_t)(h * HD_) * (B_ * T_) + (size_t)b * T_;

  auto STAGE = [&](int j, int buf) {
    const u16* krow = kbase + (size_t)(j * 64) * KVSTRIDE_;
    const u16* vrow = vtbase + j * 64;
#pragma unroll
    for (int i = 0; i < 4; ++i) {
      int chunk = i * 256 + tid;  // 0..1023
      int krowi = chunk >> 4, kslot = (chunk & 15) ^ (krowi & 7);
      gload16(krow + (size_t)krowi * KVSTRIDE_ + kslot * 8, (void*)(&Ks[buf][0] + chunk * 8));
      int vrowi = chunk >> 3, vslot = (chunk & 7) ^ (vrowi & 7);
      gload16(vrow + (size_t)vrowi * (B_ * T_) + vslot * 8, (void*)(&Vts[buf][0] + chunk * 8));
    }
  };

  STAGE(0, 0);
  __syncthreads();  // vmcnt(0) drain -> tile 0 ready
  int cur = 0;

  for (int j = 0; j <= qt; ++j) {
    // issue NEXT tile's loads; they complete while we compute tile j
    if (j < qt) STAGE(j + 1, cur ^ 1);

    // S = Q K^T  (rows w*16+quad*4+r, cols ni*16+c); Ks row = ni*16+c -> row%8 == c%8
    f32x4 sf[4];
#pragma unroll
    for (int ni = 0; ni < 4; ++ni) {
      f32x4 a = (f32x4){0.f, 0.f, 0.f, 0.f};
#pragma unroll
      for (int kk = 0; kk < 4; ++kk) {
        s16x8 bfr = *(const s16x8*)(&Ks[cur][(ni * 16 + c) * 128 + ((kk * 32 + quad * 8) ^ c7)]);
        a = __builtin_amdgcn_mfma_f32_16x16x32_bf16(qf[kk], bfr, a, 0, 0, 0);
      }
      sf[ni] = a;
    }
    // causal mask (only needed on the diagonal tile)
    if (j == qt) {
#pragma unroll
      for (int ni = 0; ni < 4; ++ni)
#pragma unroll
        for (int r = 0; r < 4; ++r) {
          int rowg = w * 16 + quad * 4 + r;
          int colg = ni * 16 + c;
          if (colg > rowg) sf[ni][r] = -1e30f;
        }
    }
    // online softmax (rows live across 16 lanes sharing `quad`)
    float mc[4];
#pragma unroll
    for (int r = 0; r < 4; ++r)
      mc[r] = fmaxf(fmaxf(sf[0][r], sf[1][r]), fmaxf(sf[2][r], sf[3][r]));
#pragma unroll
    for (int off = 1; off < 16; off <<= 1)
#pragma unroll
      for (int r = 0; r < 4; ++r) mc[r] = fmaxf(mc[r], __shfl_xor(mc[r], off, 64));
#pragma unroll
    for (int r = 0; r < 4; ++r) {
      float mnew = fmaxf(m_i[r], mc[r]);
      float alpha = __expf(m_i[r] - mnew);
      m_i[r] = mnew;
      lp[r] *= alpha;
#pragma unroll
      for (int ot = 0; ot < 8; ++ot) of[ot][r] *= alpha;
    }
    // p values + LOCAL l partial (no cross-lane sum here; deferred to epilogue)
#pragma unroll
    for (int ni = 0; ni < 4; ++ni)
#pragma unroll
      for (int r = 0; r < 4; ++r) {
        float p = __expf(sf[ni][r] - m_i[r]);
        sf[ni][r] = p;
        lp[r] += p;
      }
    // write P (C-layout -> LDS, rows w*16+quad*4+r), swizzled on elem bits 3-5.
    // Wave-private (wave w touches only rows 16w..16w+15): NO barrier needed.
#pragma unroll
    for (int ni = 0; ni < 4; ++ni)
#pragma unroll
      for (int r = 0; r < 4; ++r) {
        int row = w * 16 + quad * 4 + r;
        Ps[row * 64 + ((ni * 16 + c) ^ ((row & 7) * 8))] = f2bf(sf[ni][r]);
      }
    // O += P V  (A-frag of P: rows w*16+c -> row%8 == c%8; B-frag of V likewise)
    s16x8 pa[2];
    pa[0] = *(const s16x8*)(&Ps[(w * 16 + c) * 64 + ((quad * 8) ^ c7)]);
    pa[1] = *(const s16x8*)(&Ps[(w * 16 + c) * 64 + ((32 + quad * 8) ^ c7)]);
#pragma unroll
    for (int ot = 0; ot < 8; ++ot) {
#pragma unroll
      for (int kk = 0; kk < 2; ++kk) {
        s16x8 vfr = *(const s16x8*)(&Vts[cur][(ot * 16 + c) * 64 + ((kk * 32 + quad * 8) ^ c7)]);
        of[ot] = __builtin_amdgcn_mfma_f32_16x16x32_bf16(pa[kk], vfr, of[ot], 0, 0, 0);
      }
    }

    // single barrier per iteration: drains the prefetch (covered by compute)
    // and fences buf reuse across waves.
    __syncthreads();
    cur ^= 1;
  }

  // epilogue: reduce l partials across the 16 c-lanes, then O /= l, store bf16 ctx
#pragma unroll
  for (int off = 1; off < 16; off <<= 1)
#pragma unroll
    for (int r = 0; r < 4; ++r) lp[r] += __shfl_xor(lp[r], off, 64);
  float inv[4];
#pragma unroll
  for (int r = 0; r < 4; ++r) inv[r] = 1.0f / lp[r];
  u16* obase = O + ((size_t)(b * T_ + q0) * H_ + h) * HD_;
#pragma unroll
  for (int ot = 0; ot < 8; ++ot)
#pragma unroll
    for (int r = 0; r < 4; ++r)
      obase[(size_t)(w * 16 + quad * 4 + r) * KVSTRIDE_ + ot * 16 + c] = f2bf(of[ot][r] * inv[r]);
}

// ---------------- launch ----------------
extern "C" void kernel_launch(void* const* d_in, const int* in_sizes, int n_in,
                              void* d_out, int out_size, void* d_ws, size_t ws_size,
                              hipStream_t stream) {
  const float* x = (const float*)d_in[0];
  const float* Wq = (const float*)d_in[1];
  const float* Wk = (const float*)d_in[2];
  const float* Wv = (const float*)d_in[3];
  const float* Wo = (const float*)d_in[4];
  const float* qw = (const float*)d_in[5];
  const float* kw = (const float*)d_in[6];
  float* out = (float*)d_out;

  const size_t xE = (size_t)B_ * T_ * D_;   // 8388608
  const size_t wE = (size_t)D_ * H_ * HD_;  // 4194304
  const size_t need = xE * 2 * 5 + wE * 2 * 4;  // ~112 MB
  if (ws_size < need) return;

  char* ws = (char*)d_ws;
  u16* xb = (u16*)ws;    ws += xE * 2;
  u16* wqkb = (u16*)ws;  ws += wE * 2 * 2;  // Wq || Wk adjacent -> one fused GEMM
  u16* wvb = (u16*)ws;   ws += wE * 2;
  u16* wob = (u16*)ws;   ws += wE * 2;
  u16* qb = (u16*)ws;    ws += xE * 2;
  u16* kb = (u16*)ws;    ws += xE * 2;
  u16* vtb = (u16*)ws;   ws += xE * 2;   // V^T: [H*HD][B*T]
  u16* ctxb = (u16*)ws;  ws += xE * 2;

  cvt_f32_bf16<<<xE / 1024, 256, 0, stream>>>(x, xb, (int)(xE / 4));
  cvt_f32_bf16<<<wE / 1024, 256, 0, stream>>>(Wq, wqkb, (int)(wE / 4));
  cvt_f32_bf16<<<wE / 1024, 256, 0, stream>>>(Wk, wqkb + wE, (int)(wE / 4));
  cvt_f32_bf16<<<wE / 1024, 256, 0, stream>>>(Wv, wvb, (int)(wE / 4));
  cvt_f32_bf16<<<wE / 1024, 256, 0, stream>>>(Wo, wob, (int)(wE / 4));

  // fused QK GEMM: C[4096 tok][4096] = xb * (Wq||Wk)^T, split into qb/kb
  dim3 gqk(32, 32);
  gemm_btn<2><<<gqk, 256, 0, stream>>>(xb, wqkb, qb, kb, 4096, 4096, 2048);
  // V^T = Wv * x^T : M=2048 (o), N=4096 (tokens)
  dim3 ggv(32, 16);
  gemm_btn<1><<<ggv, 256, 0, stream>>>(wvb, xb, vtb, nullptr, 2048, 4096, 2048);

  rmsnorm_rope<<<16384, 256, 0, stream>>>(qb, qw, QSCALE_);
  rmsnorm_rope<<<16384, 256, 0, stream>>>(kb, kw, 1.0f);

  attn_fwd<<<B_ * H_ * (T_ / 64), 256, 0, stream>>>(qb, kb, vtb, ctxb);

  dim3 gg(16, 32);
  gemm_btn<0><<<gg, 256, 0, stream>>>(ctxb, wob, out, nullptr, 4096, 2048, 2048);
}

// Round 5
// 386.864 us; speedup vs baseline: 1.2029x; 1.0281x over previous
//
#include <hip/hip_runtime.h>
#include <cstdint>
#include <cstddef>

#define B_ 2
#define T_ 2048
#define D_ 2048
#define H_ 16
#define HD_ 128
#define EPS_ 1e-6f
#define QSCALE_ 0.08838834764831845f  // 1/sqrt(128)
#define KVSTRIDE_ (H_ * HD_)          // 2048 elems between consecutive t

typedef unsigned short u16;
typedef short s16x8 __attribute__((ext_vector_type(8)));
typedef float f32x4 __attribute__((ext_vector_type(4)));

__device__ __forceinline__ float bf2f(u16 h) {
  union { unsigned int u; float f; } v;
  v.u = ((unsigned int)h) << 16;
  return v.f;
}
__device__ __forceinline__ u16 f2bf(float f) {
  union { float f; unsigned int u; } v;
  v.f = f;
  unsigned int r = v.u + 0x7FFFu + ((v.u >> 16) & 1u);  // round-to-nearest-even
  return (u16)(r >> 16);
}

// async global->LDS, 16B per lane (LDS dest = wave-uniform base + lane*16)
__device__ __forceinline__ void gload16(const void* g, void* l) {
  __builtin_amdgcn_global_load_lds(
      (const __attribute__((address_space(1))) unsigned int*)g,
      (__attribute__((address_space(3))) unsigned int*)l, 16, 0, 0);
}

// ---------------- fp32 -> bf16 cast ----------------
__global__ void cvt_f32_bf16(const float* __restrict__ in, u16* __restrict__ out, int n4) {
  int i = blockIdx.x * blockDim.x + threadIdx.x;
  if (i < n4) {
    float4 v = ((const float4*)in)[i];
    ((ushort4*)out)[i] = make_ushort4(f2bf(v.x), f2bf(v.y), f2bf(v.z), f2bf(v.w));
  }
}

// ---------------- bf16 GEMM: C[M,N] = A[M,K] * Bm[N,K]^T ----------------
// R7: counted-vmcnt 2-tiles-ahead pipeline (T4). R6's __syncthreads carried an
// implicit vmcnt(0) that drained the prefetch issued the SAME iteration (only
// ~350cy of cover vs 200-900cy load latency; m233: this stall = ~72% of a
// 2-phase loop). Now raw s_barrier + counted waits:
//   prologue: STAGE(0,b0); STAGE(1,b1); vmcnt(8) [tile0 landed]; bar
//   iter t:   ds_read frags(buf[t&1]); lgkmcnt(0); bar   // reads retired
//             STAGE(t+2 -> buf[t&1])                     // refill freed buf
//             32x MFMA
//             vmcnt(8) [tile t+1 landed; t+2 in flight]; bar
// Each tile's loads get ~2 compute phases of cover; vmcnt never drains to 0
// in steady state (FIFO semantics per m135: 16 outstanding, wait 8 = oldest
// tile landed). Race audit: DMA into buf[t&1] ordered after all waves'
// lgkmcnt(0)+bar; tile t+2 writes ordered before reads by end-of-(t+1)
// vmcnt+bar; t=NT-2 uses vmcnt(0) so the loop exits fully drained.
// MODE: 0 = f32 out, 1 = bf16 out, 2 = QK-split (bf16; n0<2048 -> Cout,
// else Cout2 with col-2048; both stride 2048). n0 is block-uniform.
template <int MODE>
__global__ __launch_bounds__(256, 2) void gemm_btn(const u16* __restrict__ A,
                                                   const u16* __restrict__ Bm,
                                                   void* __restrict__ Cout,
                                                   void* __restrict__ Cout2,
                                                   int M, int N, int K) {
  __shared__ u16 As[2][2 * 128 * 32];
  __shared__ u16 Bs[2][2 * 128 * 32];
  const int tid = threadIdx.x;
  const int w = tid >> 6, lane = tid & 63, quad = lane >> 4, c = lane & 15;
  const int wm = w & 1, wn = w >> 1;
  const int m0 = blockIdx.y * 128, n0 = blockIdx.x * 128;
  const int NT = K >> 6;  // always 32 here (K=2048)

  f32x4 acc[4][4];
#pragma unroll
  for (int i = 0; i < 4; ++i)
#pragma unroll
    for (int j = 0; j < 4; ++j) acc[i][j] = (f32x4){0.f, 0.f, 0.f, 0.f};

  // stage one 128x64 A-tile + B-tile into buf (layout [kc][128][32], 64B rows)
  // 8 global_load_lds instructions per thread => per-wave vmcnt +8 per STAGE.
  auto STAGE = [&](int t, int buf) {
    int k0 = t << 6;
#pragma unroll
    for (int i = 0; i < 4; ++i) {
      int chunk = (w * 4 + i) * 64 + lane;    // 0..1023
      int kc = chunk >> 9;                    // half-tile select (LDS-contiguous)
      int within = chunk & 511;
      int row = within >> 2, cc = within & 3; // 128 rows x 4 8-elem chunks
      gload16(A + (size_t)(m0 + row) * K + k0 + kc * 32 + cc * 8, (void*)(&As[buf][0] + chunk * 8));
      gload16(Bm + (size_t)(n0 + row) * K + k0 + kc * 32 + cc * 8, (void*)(&Bs[buf][0] + chunk * 8));
    }
  };

  STAGE(0, 0);
  STAGE(1, 1);
  asm volatile("s_waitcnt vmcnt(8)" ::: "memory");  // tile 0 landed (tile 1 in flight)
  __builtin_amdgcn_s_barrier();

  for (int t = 0; t < NT; ++t) {
    const int cur = t & 1;
    s16x8 af[4][2], bf[4][2];
#pragma unroll
    for (int kc = 0; kc < 2; ++kc) {
#pragma unroll
      for (int mi = 0; mi < 4; ++mi)
        af[mi][kc] = *(const s16x8*)(&As[cur][0] + kc * 4096 + (wm * 64 + mi * 16 + c) * 32 + quad * 8);
#pragma unroll
      for (int ni = 0; ni < 4; ++ni)
        bf[ni][kc] = *(const s16x8*)(&Bs[cur][0] + kc * 4096 + (wn * 64 + ni * 16 + c) * 32 + quad * 8);
    }
    // all reads of buf[cur] retired before any wave's DMA may overwrite it
    asm volatile("s_waitcnt lgkmcnt(0)" ::: "memory");
    __builtin_amdgcn_s_barrier();
    if (t + 2 < NT) STAGE(t + 2, cur);  // 2 tiles ahead into the freed buffer

#pragma unroll
    for (int kc = 0; kc < 2; ++kc)
#pragma unroll
      for (int mi = 0; mi < 4; ++mi)
#pragma unroll
        for (int ni = 0; ni < 4; ++ni)
          acc[mi][ni] = __builtin_amdgcn_mfma_f32_16x16x32_bf16(af[mi][kc], bf[ni][kc], acc[mi][ni], 0, 0, 0);

    if (t + 1 < NT) {
      if (t + 2 < NT)
        asm volatile("s_waitcnt vmcnt(8)" ::: "memory");  // tile t+1 landed, t+2 in flight
      else
        asm volatile("s_waitcnt vmcnt(0)" ::: "memory");  // last refill: full drain
      __builtin_amdgcn_s_barrier();
    }
  }

  // epilogue (no outstanding DMA: drained at t=NT-2)
  u16* dst16 = (u16*)Cout;
  int coloff = 0, nstride = N;
  if (MODE == 2) {
    nstride = 2048;
    if (n0 >= 2048) { dst16 = (u16*)Cout2; coloff = -2048; }
  }
#pragma unroll
  for (int mi = 0; mi < 4; ++mi)
#pragma unroll
    for (int ni = 0; ni < 4; ++ni)
#pragma unroll
      for (int r = 0; r < 4; ++r) {
        int row = m0 + wm * 64 + mi * 16 + quad * 4 + r;
        int col = n0 + wn * 64 + ni * 16 + c + coloff;
        float v = acc[mi][ni][r];
        if (MODE == 0)
          ((float*)Cout)[(size_t)row * N + col] = v;
        else
          dst16[(size_t)row * nstride + col] = f2bf(v);
      }
}

// ---------------- fused RMSNorm + interleaved RoPE (in-place on bf16) ----------------
__global__ void rmsnorm_rope(u16* __restrict__ x, const float* __restrict__ nw, float outscale) {
  const int tid = threadIdx.x;
  const int w = tid >> 6, lane = tid & 63;
  const int vec = blockIdx.x * 4 + w;   // (b*T + t)*H + h
  const int t = (vec >> 4) & (T_ - 1);  // /H % T
  u16* base = x + (size_t)vec * HD_;
  unsigned int pk = *(const unsigned int*)(base + lane * 2);
  float e = bf2f((u16)(pk & 0xFFFFu));
  float o = bf2f((u16)(pk >> 16));
  float ss = e * e + o * o;
#pragma unroll
  for (int off = 1; off < 64; off <<= 1) ss += __shfl_xor(ss, off, 64);
  float rn = rsqrtf(ss * (1.0f / HD_) + EPS_);
  float we = nw[lane * 2], wo = nw[lane * 2 + 1];
  e = e * rn * we;
  o = o * rn * wo;
  float freq = expf(-(float)lane * (9.210340371976184f / 64.0f));  // 10000^(-lane/64)
  float ang = (float)t * freq;
  float sn, cs;
  sincosf(ang, &sn, &cs);
  float re = (e * cs - o * sn) * outscale;
  float ro = (e * sn + o * cs) * outscale;
  *(unsigned int*)(base + lane * 2) = ((unsigned int)f2bf(ro) << 16) | (unsigned int)f2bf(re);
}

// ---------------- causal flash attention, Br=Bc=64, bf16 MFMA (R5, unchanged) ----------------
__global__ __launch_bounds__(256, 2) void attn_fwd(const u16* __restrict__ Q,
                                                   const u16* __restrict__ Kg,
                                                   const u16* __restrict__ Vt,
                                                   u16* __restrict__ O) {
  __shared__ u16 Ks[2][64 * 128];   // K rows (s-major, d contig), slot-swizzled
  __shared__ u16 Vts[2][128 * 64];  // V^T rows (d-major, s contig), slot-swizzled
  __shared__ u16 Ps[64 * 64];       // P round-trip (wave-private), slot-swizzled
  const int tid = threadIdx.x;
  const int w = tid >> 6, lane = tid & 63, quad = lane >> 4, c = lane & 15;
  const int c7 = (c & 7) * 8;    // read-side XOR term (row % 8 == c % 8 for all frag reads)
  const int bid = blockIdx.x;
  const int qt = 31 - (bid >> 5);  // heavy (qt=31) blocks dispatch first
  const int h = bid & 15;
  const int b = (bid >> 4) & 1;
  const int q0 = qt * 64;

  // Q fragments, kept in registers (rows w*16+c, A-layout)
  s16x8 qf[4];
  const u16* qbase = Q + ((size_t)(b * T_ + q0 + w * 16 + c) * H_ + h) * HD_;
#pragma unroll
  for (int kk = 0; kk < 4; ++kk) qf[kk] = *(const s16x8*)(qbase + kk * 32 + quad * 8);

  f32x4 of[8];
#pragma unroll
  for (int i = 0; i < 8; ++i) of[i] = (f32x4){0.f, 0.f, 0.f, 0.f};
  float m_i[4] = {-1e30f, -1e30f, -1e30f, -1e30f};
  float lp[4] = {0.f, 0.f, 0.f, 0.f};  // PER-LANE partial of l (reduced in epilogue)

  const u16* kbase = Kg + ((size_t)b * T_ * H_ + h) * HD_;
  const u16* vtbase = Vt + (size_t)(h * HD_) * (B_ * T_) + (size_t)b * T_;

  auto STAGE = [&](int j, int buf) {
    const u16* krow = kbase + (size_t)(j * 64) * KVSTRIDE_;
    const u16* vrow = vtbase + j * 64;
#pragma unroll
    for (int i = 0; i < 4; ++i) {
      int chunk = i * 256 + tid;  // 0..1023
      int krowi = chunk >> 4, kslot = (chunk & 15) ^ (krowi & 7);
      gload16(krow + (size_t)krowi * KVSTRIDE_ + kslot * 8, (void*)(&Ks[buf][0] + chunk * 8));
      int vrowi = chunk >> 3, vslot = (chunk & 7) ^ (vrowi & 7);
      gload16(vrow + (size_t)vrowi * (B_ * T_) + vslot * 8, (void*)(&Vts[buf][0] + chunk * 8));
    }
  };

  STAGE(0, 0);
  __syncthreads();  // vmcnt(0) drain -> tile 0 ready
  int cur = 0;

  for (int j = 0; j <= qt; ++j) {
    // issue NEXT tile's loads; they complete while we compute tile j
    if (j < qt) STAGE(j + 1, cur ^ 1);

    // S = Q K^T  (rows w*16+quad*4+r, cols ni*16+c); Ks row = ni*16+c -> row%8 == c%8
    f32x4 sf[4];
#pragma unroll
    for (int ni = 0; ni < 4; ++ni) {
      f32x4 a = (f32x4){0.f, 0.f, 0.f, 0.f};
#pragma unroll
      for (int kk = 0; kk < 4; ++kk) {
        s16x8 bfr = *(const s16x8*)(&Ks[cur][(ni * 16 + c) * 128 + ((kk * 32 + quad * 8) ^ c7)]);
        a = __builtin_amdgcn_mfma_f32_16x16x32_bf16(qf[kk], bfr, a, 0, 0, 0);
      }
      sf[ni] = a;
    }
    // causal mask (only needed on the diagonal tile)
    if (j == qt) {
#pragma unroll
      for (int ni = 0; ni < 4; ++ni)
#pragma unroll
        for (int r = 0; r < 4; ++r) {
          int rowg = w * 16 + quad * 4 + r;
          int colg = ni * 16 + c;
          if (colg > rowg) sf[ni][r] = -1e30f;
        }
    }
    // online softmax (rows live across 16 lanes sharing `quad`)
    float mc[4];
#pragma unroll
    for (int r = 0; r < 4; ++r)
      mc[r] = fmaxf(fmaxf(sf[0][r], sf[1][r]), fmaxf(sf[2][r], sf[3][r]));
#pragma unroll
    for (int off = 1; off < 16; off <<= 1)
#pragma unroll
      for (int r = 0; r < 4; ++r) mc[r] = fmaxf(mc[r], __shfl_xor(mc[r], off, 64));
#pragma unroll
    for (int r = 0; r < 4; ++r) {
      float mnew = fmaxf(m_i[r], mc[r]);
      float alpha = __expf(m_i[r] - mnew);
      m_i[r] = mnew;
      lp[r] *= alpha;
#pragma unroll
      for (int ot = 0; ot < 8; ++ot) of[ot][r] *= alpha;
    }
    // p values + LOCAL l partial (no cross-lane sum here; deferred to epilogue)
#pragma unroll
    for (int ni = 0; ni < 4; ++ni)
#pragma unroll
      for (int r = 0; r < 4; ++r) {
        float p = __expf(sf[ni][r] - m_i[r]);
        sf[ni][r] = p;
        lp[r] += p;
      }
    // write P (C-layout -> LDS, rows w*16+quad*4+r), swizzled on elem bits 3-5.
    // Wave-private (wave w touches only rows 16w..16w+15): NO barrier needed.
#pragma unroll
    for (int ni = 0; ni < 4; ++ni)
#pragma unroll
      for (int r = 0; r < 4; ++r) {
        int row = w * 16 + quad * 4 + r;
        Ps[row * 64 + ((ni * 16 + c) ^ ((row & 7) * 8))] = f2bf(sf[ni][r]);
      }
    // O += P V  (A-frag of P: rows w*16+c -> row%8 == c%8; B-frag of V likewise)
    s16x8 pa[2];
    pa[0] = *(const s16x8*)(&Ps[(w * 16 + c) * 64 + ((quad * 8) ^ c7)]);
    pa[1] = *(const s16x8*)(&Ps[(w * 16 + c) * 64 + ((32 + quad * 8) ^ c7)]);
#pragma unroll
    for (int ot = 0; ot < 8; ++ot) {
#pragma unroll
      for (int kk = 0; kk < 2; ++kk) {
        s16x8 vfr = *(const s16x8*)(&Vts[cur][(ot * 16 + c) * 64 + ((kk * 32 + quad * 8) ^ c7)]);
        of[ot] = __builtin_amdgcn_mfma_f32_16x16x32_bf16(pa[kk], vfr, of[ot], 0, 0, 0);
      }
    }

    // single barrier per iteration: drains the prefetch (covered by compute)
    // and fences buf reuse across waves.
    __syncthreads();
    cur ^= 1;
  }

  // epilogue: reduce l partials across the 16 c-lanes, then O /= l, store bf16 ctx
#pragma unroll
  for (int off = 1; off < 16; off <<= 1)
#pragma unroll
    for (int r = 0; r < 4; ++r) lp[r] += __shfl_xor(lp[r], off, 64);
  float inv[4];
#pragma unroll
  for (int r = 0; r < 4; ++r) inv[r] = 1.0f / lp[r];
  u16* obase = O + ((size_t)(b * T_ + q0) * H_ + h) * HD_;
#pragma unroll
  for (int ot = 0; ot < 8; ++ot)
#pragma unroll
    for (int r = 0; r < 4; ++r)
      obase[(size_t)(w * 16 + quad * 4 + r) * KVSTRIDE_ + ot * 16 + c] = f2bf(of[ot][r] * inv[r]);
}

// ---------------- launch ----------------
extern "C" void kernel_launch(void* const* d_in, const int* in_sizes, int n_in,
                              void* d_out, int out_size, void* d_ws, size_t ws_size,
                              hipStream_t stream) {
  const float* x = (const float*)d_in[0];
  const float* Wq = (const float*)d_in[1];
  const float* Wk = (const float*)d_in[2];
  const float* Wv = (const float*)d_in[3];
  const float* Wo = (const float*)d_in[4];
  const float* qw = (const float*)d_in[5];
  const float* kw = (const float*)d_in[6];
  float* out = (float*)d_out;

  const size_t xE = (size_t)B_ * T_ * D_;   // 8388608
  const size_t wE = (size_t)D_ * H_ * HD_;  // 4194304
  const size_t need = xE * 2 * 5 + wE * 2 * 4;  // ~112 MB
  if (ws_size < need) return;

  char* ws = (char*)d_ws;
  u16* xb = (u16*)ws;    ws += xE * 2;
  u16* wqkb = (u16*)ws;  ws += wE * 2 * 2;  // Wq || Wk adjacent -> one fused GEMM
  u16* wvb = (u16*)ws;   ws += wE * 2;
  u16* wob = (u16*)ws;   ws += wE * 2;
  u16* qb = (u16*)ws;    ws += xE * 2;
  u16* kb = (u16*)ws;    ws += xE * 2;
  u16* vtb = (u16*)ws;   ws += xE * 2;   // V^T: [H*HD][B*T]
  u16* ctxb = (u16*)ws;  ws += xE * 2;

  cvt_f32_bf16<<<xE / 1024, 256, 0, stream>>>(x, xb, (int)(xE / 4));
  cvt_f32_bf16<<<wE / 1024, 256, 0, stream>>>(Wq, wqkb, (int)(wE / 4));
  cvt_f32_bf16<<<wE / 1024, 256, 0, stream>>>(Wk, wqkb + wE, (int)(wE / 4));
  cvt_f32_bf16<<<wE / 1024, 256, 0, stream>>>(Wv, wvb, (int)(wE / 4));
  cvt_f32_bf16<<<wE / 1024, 256, 0, stream>>>(Wo, wob, (int)(wE / 4));

  // fused QK GEMM: C[4096 tok][4096] = xb * (Wq||Wk)^T, split into qb/kb
  dim3 gqk(32, 32);
  gemm_btn<2><<<gqk, 256, 0, stream>>>(xb, wqkb, qb, kb, 4096, 4096, 2048);
  // V^T = Wv * x^T : M=2048 (o), N=4096 (tokens)
  dim3 ggv(32, 16);
  gemm_btn<1><<<ggv, 256, 0, stream>>>(wvb, xb, vtb, nullptr, 2048, 4096, 2048);

  rmsnorm_rope<<<16384, 256, 0, stream>>>(qb, qw, QSCALE_);
  rmsnorm_rope<<<16384, 256, 0, stream>>>(kb, kw, 1.0f);

  attn_fwd<<<B_ * H_ * (T_ / 64), 256, 0, stream>>>(qb, kb, vtb, ctxb);

  dim3 gg(16, 32);
  gemm_btn<0><<<gg, 256, 0, stream>>>(ctxb, wob, out, nullptr, 4096, 2048, 2048);
}